// Round 5
// baseline (283.334 us; speedup 1.0000x reference)
//
#include <hip/hip_runtime.h>
#include <hip/hip_bf16.h>

#define B_ 4
#define T_ 2048
#define D_ 1024
#define H_ 16
#define HD_ 64

typedef __bf16 bf16;
typedef __bf16 bf16x8 __attribute__((ext_vector_type(8)));
typedef __bf16 bf16x4 __attribute__((ext_vector_type(4)));
typedef float f32x4 __attribute__((ext_vector_type(4)));
typedef float f32x16 __attribute__((ext_vector_type(16)));

#define MFMA16(a, b, c) __builtin_amdgcn_mfma_f32_16x16x32_bf16(a, b, c, 0, 0, 0)
#define MFMA32(a, b, c) __builtin_amdgcn_mfma_f32_32x32x16_bf16(a, b, c, 0, 0, 0)

__device__ inline void gld_lds16(const bf16* g, bf16* l) {
  __builtin_amdgcn_global_load_lds((const __attribute__((address_space(1))) void*)g,
                                   (__attribute__((address_space(3))) void*)l, 16, 0, 0);
}

__device__ inline unsigned pkbf16(float a, float b) {
  unsigned r;
  asm("v_cvt_pk_bf16_f32 %0, %1, %2" : "=v"(r) : "v"(a), "v"(b));
  return r;
}
__device__ inline void pl32swap(unsigned& x, unsigned& y) {
  asm("v_permlane32_swap_b32 %0, %1" : "+v"(x), "+v"(y));
}

// pack 8 consecutive-kv P values (this lane + partner lane) into one B-frag
#define PACKJ(dst, S, base)                        \
  {                                                \
    unsigned w0 = pkbf16(S[base + 0], S[base + 1]); \
    unsigned w2 = pkbf16(S[base + 4], S[base + 5]); \
    pl32swap(w0, w2);                              \
    unsigned w1 = pkbf16(S[base + 2], S[base + 3]); \
    unsigned w3 = pkbf16(S[base + 6], S[base + 7]); \
    pl32swap(w1, w3);                              \
    int4 wi = {(int)w0, (int)w1, (int)w2, (int)w3}; \
    dst = __builtin_bit_cast(bf16x8, wi);          \
  }

// ---------------- convert x f32 -> bf16 ----------------
__global__ void cvt_f32_bf16(const float* __restrict__ in, bf16* __restrict__ out) {
  int i = (blockIdx.x * 256 + threadIdx.x) * 4;
  float4 v = *(const float4*)(in + i);
  bf16x4 o = {(bf16)v.x, (bf16)v.y, (bf16)v.z, (bf16)v.w};
  *(bf16x4*)(out + i) = o;
}

// ---------------- transpose f32 [R][C] -> bf16 [C][R] ----------------
__global__ void transpose_f32_bf16(const float* __restrict__ in, bf16* __restrict__ out,
                                   int R, int C) {
  __shared__ float tile[32][33];
  int c0 = blockIdx.x * 32, r0 = blockIdx.y * 32;
  int tx = threadIdx.x, ty = threadIdx.y;
#pragma unroll
  for (int i = 0; i < 4; i++)
    tile[ty + i * 8][tx] = in[(size_t)(r0 + ty + i * 8) * C + c0 + tx];
  __syncthreads();
#pragma unroll
  for (int i = 0; i < 4; i++)
    out[(size_t)(c0 + ty + i * 8) * R + r0 + tx] = (bf16)tile[tx][ty + i * 8];
}

// ---------------- transpose V bf16 [bh][T][64] -> [bh][64][T] ----------------
__global__ void transpose_v(const bf16* __restrict__ in, bf16* __restrict__ out) {
  __shared__ bf16 tile[32][33];
  int bh = blockIdx.y;
  int t0 = blockIdx.x * 32;
  int tx = threadIdx.x, ty = threadIdx.y;
  const bf16* ib = in + (size_t)bh * T_ * HD_;
  bf16* ob = out + (size_t)bh * HD_ * T_;
#pragma unroll
  for (int d0 = 0; d0 < 64; d0 += 32) {
#pragma unroll
    for (int i = 0; i < 4; i++)
      tile[ty + i * 8][tx] = ib[(size_t)(t0 + ty + i * 8) * HD_ + d0 + tx];
    __syncthreads();
#pragma unroll
    for (int i = 0; i < 4; i++)
      ob[(size_t)(d0 + ty + i * 8) * T_ + t0 + tx] = tile[tx][ty + i * 8];
    __syncthreads();
  }
}

// ---------------- 128x128 bf16 GEMM, B transposed ([N][K]) ----------------
template <int EPI>
__global__ __launch_bounds__(256) void gemm_bt(const bf16* __restrict__ A,
                                               const bf16* __restrict__ Bt,
                                               bf16* __restrict__ qb, bf16* __restrict__ kb,
                                               bf16* __restrict__ vb, float* __restrict__ fout,
                                               int M, int N, int K) {
  __shared__ __align__(16) bf16 lds_a[128 * 32];
  __shared__ __align__(16) bf16 lds_b[128 * 32];
  int n0 = blockIdx.x * 128, m0 = blockIdx.y * 128;
  int tid = threadIdx.x, wave = tid >> 6, lane = tid & 63;
  int l16 = lane & 15, lhi = lane >> 4;
  int wr = wave >> 1, wc = wave & 1;
  f32x4 acc[4][4];
#pragma unroll
  for (int mt = 0; mt < 4; mt++)
#pragma unroll
    for (int nt = 0; nt < 4; nt++) acc[mt][nt] = (f32x4){0.f, 0.f, 0.f, 0.f};

  int sr = wave * 16 + (lane >> 2);
  int scol = (lane & 3) * 8;
  const bf16* ga = A + (size_t)(m0 + sr) * K + scol;
  const bf16* gb = Bt + (size_t)(n0 + sr) * K + scol;
  bf16* la0 = &lds_a[wave * 512];
  bf16* la1 = &lds_a[2048 + wave * 512];
  bf16* lb0 = &lds_b[wave * 512];
  bf16* lb1 = &lds_b[2048 + wave * 512];

  for (int k0 = 0; k0 < K; k0 += 32) {
    gld_lds16(ga + k0, la0);
    gld_lds16(ga + (size_t)64 * K + k0, la1);
    gld_lds16(gb + k0, lb0);
    gld_lds16(gb + (size_t)64 * K + k0, lb1);
    __syncthreads();
    bf16x8 af[4], bfr[4];
#pragma unroll
    for (int mt = 0; mt < 4; mt++)
      af[mt] = *(const bf16x8*)&lds_a[(wr * 64 + mt * 16 + l16) * 32 + 8 * lhi];
#pragma unroll
    for (int nt = 0; nt < 4; nt++)
      bfr[nt] = *(const bf16x8*)&lds_b[(wc * 64 + nt * 16 + l16) * 32 + 8 * lhi];
#pragma unroll
    for (int mt = 0; mt < 4; mt++)
#pragma unroll
      for (int nt = 0; nt < 4; nt++) acc[mt][nt] = MFMA16(af[mt], bfr[nt], acc[mt][nt]);
    __syncthreads();
  }

#pragma unroll
  for (int mt = 0; mt < 4; mt++)
#pragma unroll
    for (int nt = 0; nt < 4; nt++)
#pragma unroll
      for (int rr = 0; rr < 4; rr++) {
        int row = m0 + wr * 64 + mt * 16 + 4 * lhi + rr;
        int col = n0 + wc * 64 + nt * 16 + l16;
        float v = acc[mt][nt][rr];
        if (EPI == 0) {
          int b = row >> 11, t = row & (T_ - 1);
          int sec = col >> 10, c2 = col & 1023;
          int h = c2 >> 6, d = c2 & 63;
          size_t idx = ((size_t)(b * H_ + h) * T_ + t) * HD_ + d;
          if (sec == 0)
            qb[idx] = (bf16)(v * 0.045084439f);  // D^-0.5 * log2(e): exp2-domain softmax
          else if (sec == 1)
            kb[idx] = (bf16)v;
          else
            vb[idx] = (bf16)v;
        } else {
          fout[(size_t)row * N + col] = v;
        }
      }
}

// ---------------- causal flash attention v5 ----------------
// 1-wave blocks, 32 q rows. Swapped QK^T (A=K,B=Q) 32x32x16: q = lane&31
// uniform -> softmax in-lane + one shfl. exp2-domain (log2e folded into Q).
// Tree reductions. No K reg-double-buffer: VGPR<=128 -> 4 waves/SIMD (TLP
// hides L2 latency). P packed in-register (cvt_pk + permlane32_swap).
__global__ __launch_bounds__(64, 4) void attn_kernel(const bf16* __restrict__ qbuf,
                                                     const bf16* __restrict__ kbuf,
                                                     const bf16* __restrict__ vtbuf,
                                                     bf16* __restrict__ obuf) {
  __shared__ float tlds[64 * 33];
  int bid = blockIdx.x;
  int bh = (bid & 7) * 8 + ((bid >> 3) & 7);
  int qw = (63 - (bid >> 6)) * 32;  // heavy chunks dispatched first
  int lane = threadIdx.x;
  int q = lane & 31, hi = lane >> 5;

  const bf16* Q = qbuf + (size_t)bh * T_ * HD_;
  const bf16* Kg = kbuf + (size_t)bh * T_ * HD_;
  const bf16* Vt = vtbuf + (size_t)bh * HD_ * T_;

  bf16x8 qf[4];
#pragma unroll
  for (int j = 0; j < 4; j++)
    qf[j] = *(const bf16x8*)(Q + (size_t)(qw + q) * HD_ + j * 16 + hi * 8);

  const bf16* kbase = Kg + (size_t)q * HD_ + hi * 8;
  const bf16* vbase = Vt + (size_t)q * T_ + hi * 8;

  f32x16 o1, o2;
#pragma unroll
  for (int r = 0; r < 16; r++) {
    o1[r] = 0.f;
    o2[r] = 0.f;
  }
  float m_r = -1e30f, l_r = 0.f;
  int nt = qw / 64 + 1;

  for (int t = 0; t < nt; ++t) {
    int jb = t * 64;
    // ---- K frags (L2-hit) ----
    bf16x8 kf[8];
#pragma unroll
    for (int j = 0; j < 4; j++) {
      kf[j] = *(const bf16x8*)(kbase + (size_t)jb * HD_ + j * 16);
      kf[4 + j] = *(const bf16x8*)(kbase + (size_t)(jb + 32) * HD_ + j * 16);
    }
    // ---- QK^T: S^T[kv][q] ----
    f32x16 s1, s2;
#pragma unroll
    for (int r = 0; r < 16; r++) {
      s1[r] = 0.f;
      s2[r] = 0.f;
    }
    __builtin_amdgcn_s_setprio(1);
#pragma unroll
    for (int j = 0; j < 4; j++) s1 = MFMA32(kf[j], qf[j], s1);
#pragma unroll
    for (int j = 0; j < 4; j++) s2 = MFMA32(kf[4 + j], qf[j], s2);
    __builtin_amdgcn_s_setprio(0);
    // ---- V frags (kf regs dead -> reuse); softmax covers the latency ----
    bf16x8 vf[8];
#pragma unroll
    for (int j = 0; j < 4; j++) {
      vf[j] = *(const bf16x8*)(vbase + jb + j * 16);
      vf[4 + j] = *(const bf16x8*)(vbase + 32 * T_ + jb + j * 16);
    }
    // ---- causal mask (last tile only) ----
    if (t == nt - 1) {
#pragma unroll
      for (int r = 0; r < 16; r++) {
        int kv = (r & 3) + 8 * (r >> 2) + 4 * hi;
        if (jb + kv > qw + q) s1[r] = -1e30f;
        if (jb + kv + 32 > qw + q) s2[r] = -1e30f;
      }
    }
    // ---- online softmax, tree reductions, exp2 domain ----
    float tm[8];
#pragma unroll
    for (int r = 0; r < 8; r++)
      tm[r] = fmaxf(fmaxf(s1[r], s1[r + 8]), fmaxf(s2[r], s2[r + 8]));
#pragma unroll
    for (int r = 0; r < 4; r++) tm[r] = fmaxf(tm[r], tm[r + 4]);
    float mx = fmaxf(fmaxf(tm[0], tm[1]), fmaxf(tm[2], tm[3]));
    mx = fmaxf(mx, __shfl_xor(mx, 32));
    float mn = fmaxf(m_r, mx);
    float sc = exp2f(m_r - mn);
    m_r = mn;
#pragma unroll
    for (int r = 0; r < 16; r++) s1[r] = exp2f(s1[r] - mn);
#pragma unroll
    for (int r = 0; r < 16; r++) s2[r] = exp2f(s2[r] - mn);
    float ts[8];
#pragma unroll
    for (int r = 0; r < 8; r++) ts[r] = (s1[r] + s1[r + 8]) + (s2[r] + s2[r + 8]);
#pragma unroll
    for (int r = 0; r < 4; r++) ts[r] += ts[r + 4];
    float su = (ts[0] + ts[1]) + (ts[2] + ts[3]);
    su += __shfl_xor(su, 32);
    l_r = l_r * sc + su;
#pragma unroll
    for (int r = 0; r < 16; r++) {
      o1[r] *= sc;
      o2[r] *= sc;
    }
    // ---- pack P into PV B-frags (in-register) ----
    bf16x8 pf0, pf1, pf2, pf3;
    PACKJ(pf0, s1, 0);
    PACKJ(pf1, s1, 8);
    PACKJ(pf2, s2, 0);
    PACKJ(pf3, s2, 8);
    // ---- PV: O^T[d][q] ----
    __builtin_amdgcn_s_setprio(1);
    o1 = MFMA32(vf[0], pf0, o1);
    o2 = MFMA32(vf[4], pf0, o2);
    o1 = MFMA32(vf[1], pf1, o1);
    o2 = MFMA32(vf[5], pf1, o2);
    o1 = MFMA32(vf[2], pf2, o1);
    o2 = MFMA32(vf[6], pf2, o2);
    o1 = MFMA32(vf[3], pf3, o1);
    o2 = MFMA32(vf[7], pf3, o2);
    __builtin_amdgcn_s_setprio(0);
  }

  // ---- epilogue: O^T -> LDS transpose -> coalesced bf16 stores ----
  float inv = 1.f / l_r;
#pragma unroll
  for (int r = 0; r < 16; r++) {
    int d = (r & 3) + 8 * (r >> 2) + 4 * hi;
    tlds[d * 33 + q] = o1[r] * inv;
    tlds[(32 + d) * 33 + q] = o2[r] * inv;
  }
  __syncthreads();
  int b = bh >> 4, h = bh & 15;
#pragma unroll
  for (int pass = 0; pass < 4; pass++) {
    int row = qw + pass * 8 + (lane >> 3);
    int dcol = (lane & 7) * 8;
    bf16x8 ov;
#pragma unroll
    for (int e = 0; e < 8; e++) ov[e] = (bf16)tlds[(dcol + e) * 33 + pass * 8 + (lane >> 3)];
    *(bf16x8*)(obuf + ((size_t)(b * T_ + row)) * D_ + h * 64 + dcol) = ov;
  }
}

extern "C" void kernel_launch(void* const* d_in, const int* in_sizes, int n_in, void* d_out,
                              int out_size, void* d_ws, size_t ws_size, hipStream_t stream) {
  const float* x = (const float*)d_in[0];
  const float* wqkv = (const float*)d_in[1];
  const float* wo = (const float*)d_in[2];
  float* out = (float*)d_out;
  char* ws = (char*)d_ws;

  bf16* xb = (bf16*)ws;                     // 16 MB  [8192][1024]
  bf16* wqkvt = (bf16*)(ws + (16u << 20));  // 6 MB   [3072][1024]
  bf16* wot = (bf16*)(ws + (22u << 20));    // 2 MB   [1024][1024]
  bf16* qb = (bf16*)(ws + (24u << 20));     // 16 MB  [B,H,T,64]
  bf16* kb = (bf16*)(ws + (40u << 20));     // 16 MB  [B,H,T,64]
  bf16* vb = (bf16*)(ws + (56u << 20));     // 16 MB  [B,H,T,64]
  bf16* vtb = (bf16*)(ws + (72u << 20));    // 16 MB  [B,H,64,T]
  bf16* ao = (bf16*)(ws + (88u << 20));     // 16 MB  [8192][1024]

  cvt_f32_bf16<<<8192, 256, 0, stream>>>(x, xb);
  transpose_f32_bf16<<<dim3(96, 32), dim3(32, 8), 0, stream>>>(wqkv, wqkvt, 1024, 3072);
  transpose_f32_bf16<<<dim3(32, 32), dim3(32, 8), 0, stream>>>(wo, wot, 1024, 1024);
  gemm_bt<0><<<dim3(24, 64), 256, 0, stream>>>(xb, wqkvt, qb, kb, vb, nullptr,
                                               B_ * T_, 3 * D_, D_);
  transpose_v<<<dim3(64, 64), dim3(32, 8), 0, stream>>>(vb, vtb);
  attn_kernel<<<4096, 64, 0, stream>>>(qb, kb, vtb, ao);
  gemm_bt<1><<<dim3(8, 64), 256, 0, stream>>>(ao, wot, nullptr, nullptr, nullptr, out,
                                              B_ * T_, D_, D_);
}

// Round 6
// 241.406 us; speedup vs baseline: 1.1737x; 1.1737x over previous
//
#include <hip/hip_runtime.h>
#include <hip/hip_bf16.h>

#define B_ 4
#define T_ 2048
#define D_ 1024
#define H_ 16
#define HD_ 64

typedef __bf16 bf16;
typedef __bf16 bf16x8 __attribute__((ext_vector_type(8)));
typedef __bf16 bf16x4 __attribute__((ext_vector_type(4)));
typedef float f32x4 __attribute__((ext_vector_type(4)));
typedef float f32x16 __attribute__((ext_vector_type(16)));

#define MFMA16(a, b, c) __builtin_amdgcn_mfma_f32_16x16x32_bf16(a, b, c, 0, 0, 0)
#define MFMA32(a, b, c) __builtin_amdgcn_mfma_f32_32x32x16_bf16(a, b, c, 0, 0, 0)

__device__ inline void gld_lds16(const bf16* g, bf16* l) {
  __builtin_amdgcn_global_load_lds((const __attribute__((address_space(1))) void*)g,
                                   (__attribute__((address_space(3))) void*)l, 16, 0, 0);
}

__device__ inline unsigned pkbf16(float a, float b) {
  unsigned r;
  asm("v_cvt_pk_bf16_f32 %0, %1, %2" : "=v"(r) : "v"(a), "v"(b));
  return r;
}
__device__ inline void pl32swap(unsigned& x, unsigned& y) {
  asm("v_permlane32_swap_b32 %0, %1" : "+v"(x), "+v"(y));
}

// pack 8 consecutive-kv P values (this lane + partner lane) into one B-frag
#define PACKJ(dst, S, base)                        \
  {                                                \
    unsigned w0 = pkbf16(S[base + 0], S[base + 1]); \
    unsigned w2 = pkbf16(S[base + 4], S[base + 5]); \
    pl32swap(w0, w2);                              \
    unsigned w1 = pkbf16(S[base + 2], S[base + 3]); \
    unsigned w3 = pkbf16(S[base + 6], S[base + 7]); \
    pl32swap(w1, w3);                              \
    int4 wi = {(int)w0, (int)w1, (int)w2, (int)w3}; \
    dst = __builtin_bit_cast(bf16x8, wi);          \
  }

// ---------------- convert x f32 -> bf16 ----------------
__global__ void cvt_f32_bf16(const float* __restrict__ in, bf16* __restrict__ out) {
  int i = (blockIdx.x * 256 + threadIdx.x) * 4;
  float4 v = *(const float4*)(in + i);
  bf16x4 o = {(bf16)v.x, (bf16)v.y, (bf16)v.z, (bf16)v.w};
  *(bf16x4*)(out + i) = o;
}

// ---------------- transpose f32 [R][C] -> bf16 [C][R] ----------------
__global__ void transpose_f32_bf16(const float* __restrict__ in, bf16* __restrict__ out,
                                   int R, int C) {
  __shared__ float tile[32][33];
  int c0 = blockIdx.x * 32, r0 = blockIdx.y * 32;
  int tx = threadIdx.x, ty = threadIdx.y;
#pragma unroll
  for (int i = 0; i < 4; i++)
    tile[ty + i * 8][tx] = in[(size_t)(r0 + ty + i * 8) * C + c0 + tx];
  __syncthreads();
#pragma unroll
  for (int i = 0; i < 4; i++)
    out[(size_t)(c0 + ty + i * 8) * R + r0 + tx] = (bf16)tile[tx][ty + i * 8];
}

// ---------------- transpose V bf16 [bh][T][64] -> [bh][64][T] ----------------
__global__ void transpose_v(const bf16* __restrict__ in, bf16* __restrict__ out) {
  __shared__ bf16 tile[32][33];
  int bh = blockIdx.y;
  int t0 = blockIdx.x * 32;
  int tx = threadIdx.x, ty = threadIdx.y;
  const bf16* ib = in + (size_t)bh * T_ * HD_;
  bf16* ob = out + (size_t)bh * HD_ * T_;
#pragma unroll
  for (int d0 = 0; d0 < 64; d0 += 32) {
#pragma unroll
    for (int i = 0; i < 4; i++)
      tile[ty + i * 8][tx] = ib[(size_t)(t0 + ty + i * 8) * HD_ + d0 + tx];
    __syncthreads();
#pragma unroll
    for (int i = 0; i < 4; i++)
      ob[(size_t)(d0 + ty + i * 8) * T_ + t0 + tx] = tile[tx][ty + i * 8];
    __syncthreads();
  }
}

// ---------------- 128x128 bf16 GEMM, B transposed ([N][K]) ----------------
// 2-phase double-buffered staging (T3 minimum): STAGE(next) issued before
// compute(cur); single barrier per K-step (its implicit vmcnt(0) drain
// guarantees the staged tile is ready for the NEXT iteration).
template <int EPI>
__global__ __launch_bounds__(256) void gemm_bt(const bf16* __restrict__ A,
                                               const bf16* __restrict__ Bt,
                                               bf16* __restrict__ qb, bf16* __restrict__ kb,
                                               bf16* __restrict__ vb, float* __restrict__ fout,
                                               int M, int N, int K) {
  __shared__ __align__(16) bf16 lds_a[2][128 * 32];
  __shared__ __align__(16) bf16 lds_b[2][128 * 32];
  int n0 = blockIdx.x * 128, m0 = blockIdx.y * 128;
  int tid = threadIdx.x, wave = tid >> 6, lane = tid & 63;
  int l16 = lane & 15, lhi = lane >> 4;
  int wr = wave >> 1, wc = wave & 1;
  f32x4 acc[4][4];
#pragma unroll
  for (int mt = 0; mt < 4; mt++)
#pragma unroll
    for (int nt = 0; nt < 4; nt++) acc[mt][nt] = (f32x4){0.f, 0.f, 0.f, 0.f};

  int sr = wave * 16 + (lane >> 2);
  int scol = (lane & 3) * 8;
  const bf16* ga = A + (size_t)(m0 + sr) * K + scol;
  const bf16* gb = Bt + (size_t)(n0 + sr) * K + scol;

  auto STAGE = [&](int buf, int k0) {
    gld_lds16(ga + k0, &lds_a[buf][wave * 512]);
    gld_lds16(ga + (size_t)64 * K + k0, &lds_a[buf][2048 + wave * 512]);
    gld_lds16(gb + k0, &lds_b[buf][wave * 512]);
    gld_lds16(gb + (size_t)64 * K + k0, &lds_b[buf][2048 + wave * 512]);
  };

  STAGE(0, 0);
  __syncthreads();
  int NT = K >> 5;
  for (int t = 0; t < NT; t++) {
    if (t + 1 < NT) STAGE((t + 1) & 1, (t + 1) * 32);
    const bf16* la = lds_a[t & 1];
    const bf16* lb = lds_b[t & 1];
    bf16x8 af[4], bfr[4];
#pragma unroll
    for (int mt = 0; mt < 4; mt++)
      af[mt] = *(const bf16x8*)&la[(wr * 64 + mt * 16 + l16) * 32 + 8 * lhi];
#pragma unroll
    for (int nt = 0; nt < 4; nt++)
      bfr[nt] = *(const bf16x8*)&lb[(wc * 64 + nt * 16 + l16) * 32 + 8 * lhi];
    __builtin_amdgcn_s_setprio(1);
#pragma unroll
    for (int mt = 0; mt < 4; mt++)
#pragma unroll
      for (int nt = 0; nt < 4; nt++) acc[mt][nt] = MFMA16(af[mt], bfr[nt], acc[mt][nt]);
    __builtin_amdgcn_s_setprio(0);
    __syncthreads();
  }

#pragma unroll
  for (int mt = 0; mt < 4; mt++)
#pragma unroll
    for (int nt = 0; nt < 4; nt++)
#pragma unroll
      for (int rr = 0; rr < 4; rr++) {
        int row = m0 + wr * 64 + mt * 16 + 4 * lhi + rr;
        int col = n0 + wc * 64 + nt * 16 + l16;
        float v = acc[mt][nt][rr];
        if (EPI == 0) {
          int b = row >> 11, t = row & (T_ - 1);
          int sec = col >> 10, c2 = col & 1023;
          int h = c2 >> 6, d = c2 & 63;
          size_t idx = ((size_t)(b * H_ + h) * T_ + t) * HD_ + d;
          if (sec == 0)
            qb[idx] = (bf16)(v * 0.045084439f);  // D^-0.5 * log2(e): exp2-domain softmax
          else if (sec == 1)
            kb[idx] = (bf16)v;
          else
            vb[idx] = (bf16)v;
        } else {
          fout[(size_t)row * N + col] = v;
        }
      }
}

// ---------------- causal flash attention v6 ----------------
// R4 structure (1-wave blocks, swapped QK^T 32x32, K reg double-buffer
// prefetch, in-register P pack) + exp2-domain softmax, tree reductions,
// defer-rescale (skip O-scale when max growth <= 8 in log2 domain).
__global__ __launch_bounds__(64) void attn_kernel(const bf16* __restrict__ qbuf,
                                                  const bf16* __restrict__ kbuf,
                                                  const bf16* __restrict__ vtbuf,
                                                  bf16* __restrict__ obuf) {
  __shared__ float tlds[64 * 33];
  int bid = blockIdx.x;
  int bh = (bid & 7) * 8 + ((bid >> 3) & 7);
  int qw = (63 - (bid >> 6)) * 32;  // heavy chunks dispatched first
  int lane = threadIdx.x;
  int q = lane & 31, hi = lane >> 5;

  const bf16* Q = qbuf + (size_t)bh * T_ * HD_;
  const bf16* Kg = kbuf + (size_t)bh * T_ * HD_;
  const bf16* Vt = vtbuf + (size_t)bh * HD_ * T_;

  bf16x8 qf[4];
#pragma unroll
  for (int j = 0; j < 4; j++)
    qf[j] = *(const bf16x8*)(Q + (size_t)(qw + q) * HD_ + j * 16 + hi * 8);

  const bf16* kbase = Kg + (size_t)q * HD_ + hi * 8;
  const bf16* vbase = Vt + (size_t)q * T_ + hi * 8;

  f32x16 o1, o2;
#pragma unroll
  for (int r = 0; r < 16; r++) {
    o1[r] = 0.f;
    o2[r] = 0.f;
  }
  float m_r = -1e30f, l_r = 0.f;
  int nt = qw / 64 + 1;

  bf16x8 kA[8], kB[8];
#pragma unroll
  for (int j = 0; j < 4; j++) {
    kA[j] = *(const bf16x8*)(kbase + j * 16);
    kA[4 + j] = *(const bf16x8*)(kbase + 32 * HD_ + j * 16);
  }

  auto body = [&](bf16x8(&kc)[8], bf16x8(&kp)[8], int t) {
    int jb = t * 64;
    // ---- QK^T: S^T[kv][q] ----
    f32x16 s1, s2;
#pragma unroll
    for (int r = 0; r < 16; r++) {
      s1[r] = 0.f;
      s2[r] = 0.f;
    }
    __builtin_amdgcn_s_setprio(1);
#pragma unroll
    for (int j = 0; j < 4; j++) s1 = MFMA32(kc[j], qf[j], s1);
#pragma unroll
    for (int j = 0; j < 4; j++) s2 = MFMA32(kc[4 + j], qf[j], s2);
    __builtin_amdgcn_s_setprio(0);
    // ---- prefetch next K tile (hidden under softmax+PV) ----
    if (t + 1 < nt) {
      int jn = (jb + 64) * HD_;
#pragma unroll
      for (int j = 0; j < 4; j++) {
        kp[j] = *(const bf16x8*)(kbase + jn + j * 16);
        kp[4 + j] = *(const bf16x8*)(kbase + jn + 32 * HD_ + j * 16);
      }
    }
    // ---- V frags for current tile (independent of softmax) ----
    bf16x8 vf[8];
#pragma unroll
    for (int j = 0; j < 4; j++) {
      vf[j] = *(const bf16x8*)(vbase + jb + j * 16);
      vf[4 + j] = *(const bf16x8*)(vbase + 32 * T_ + jb + j * 16);
    }
    // ---- causal mask (last tile only) ----
    if (t == nt - 1) {
#pragma unroll
      for (int r = 0; r < 16; r++) {
        int kv = (r & 3) + 8 * (r >> 2) + 4 * hi;
        if (jb + kv > qw + q) s1[r] = -1e30f;
        if (jb + kv + 32 > qw + q) s2[r] = -1e30f;
      }
    }
    // ---- online softmax: tree max, exp2 domain, defer-rescale ----
    float tm[8];
#pragma unroll
    for (int r = 0; r < 8; r++)
      tm[r] = fmaxf(fmaxf(s1[r], s1[r + 8]), fmaxf(s2[r], s2[r + 8]));
#pragma unroll
    for (int r = 0; r < 4; r++) tm[r] = fmaxf(tm[r], tm[r + 4]);
    float mx = fmaxf(fmaxf(tm[0], tm[1]), fmaxf(tm[2], tm[3]));
    mx = fmaxf(mx, __shfl_xor(mx, 32));
    bool defer = __all(mx <= m_r + 8.f);
    if (!defer) {
      float mn = fmaxf(m_r, mx);
      float sc = exp2f(m_r - mn);
      m_r = mn;
      l_r *= sc;
#pragma unroll
      for (int r = 0; r < 16; r++) {
        o1[r] *= sc;
        o2[r] *= sc;
      }
    }
#pragma unroll
    for (int r = 0; r < 16; r++) s1[r] = exp2f(s1[r] - m_r);
#pragma unroll
    for (int r = 0; r < 16; r++) s2[r] = exp2f(s2[r] - m_r);
    float ts[8];
#pragma unroll
    for (int r = 0; r < 8; r++) ts[r] = (s1[r] + s1[r + 8]) + (s2[r] + s2[r + 8]);
#pragma unroll
    for (int r = 0; r < 4; r++) ts[r] += ts[r + 4];
    float su = (ts[0] + ts[1]) + (ts[2] + ts[3]);
    su += __shfl_xor(su, 32);
    l_r += su;
    // ---- pack P into PV B-frags (in-register) ----
    bf16x8 pf0, pf1, pf2, pf3;
    PACKJ(pf0, s1, 0);
    PACKJ(pf1, s1, 8);
    PACKJ(pf2, s2, 0);
    PACKJ(pf3, s2, 8);
    // ---- PV: O^T[d][q] ----
    __builtin_amdgcn_s_setprio(1);
    o1 = MFMA32(vf[0], pf0, o1);
    o2 = MFMA32(vf[4], pf0, o2);
    o1 = MFMA32(vf[1], pf1, o1);
    o2 = MFMA32(vf[5], pf1, o2);
    o1 = MFMA32(vf[2], pf2, o1);
    o2 = MFMA32(vf[6], pf2, o2);
    o1 = MFMA32(vf[3], pf3, o1);
    o2 = MFMA32(vf[7], pf3, o2);
    __builtin_amdgcn_s_setprio(0);
  };

  int t = 0;
  while (true) {
    body(kA, kB, t);
    if (++t == nt) break;
    body(kB, kA, t);
    if (++t == nt) break;
  }

  // ---- epilogue: O^T -> LDS transpose -> coalesced bf16 stores ----
  float inv = 1.f / l_r;
#pragma unroll
  for (int r = 0; r < 16; r++) {
    int d = (r & 3) + 8 * (r >> 2) + 4 * hi;
    tlds[d * 33 + q] = o1[r] * inv;
    tlds[(32 + d) * 33 + q] = o2[r] * inv;
  }
  __syncthreads();
  int b = bh >> 4, h = bh & 15;
#pragma unroll
  for (int pass = 0; pass < 4; pass++) {
    int row = qw + pass * 8 + (lane >> 3);
    int dcol = (lane & 7) * 8;
    bf16x8 ov;
#pragma unroll
    for (int e = 0; e < 8; e++) ov[e] = (bf16)tlds[(dcol + e) * 33 + pass * 8 + (lane >> 3)];
    *(bf16x8*)(obuf + ((size_t)(b * T_ + row)) * D_ + h * 64 + dcol) = ov;
  }
}

extern "C" void kernel_launch(void* const* d_in, const int* in_sizes, int n_in, void* d_out,
                              int out_size, void* d_ws, size_t ws_size, hipStream_t stream) {
  const float* x = (const float*)d_in[0];
  const float* wqkv = (const float*)d_in[1];
  const float* wo = (const float*)d_in[2];
  float* out = (float*)d_out;
  char* ws = (char*)d_ws;

  bf16* xb = (bf16*)ws;                     // 16 MB  [8192][1024]
  bf16* wqkvt = (bf16*)(ws + (16u << 20));  // 6 MB   [3072][1024]
  bf16* wot = (bf16*)(ws + (22u << 20));    // 2 MB   [1024][1024]
  bf16* qb = (bf16*)(ws + (24u << 20));     // 16 MB  [B,H,T,64]
  bf16* kb = (bf16*)(ws + (40u << 20));     // 16 MB  [B,H,T,64]
  bf16* vb = (bf16*)(ws + (56u << 20));     // 16 MB  [B,H,T,64]
  bf16* vtb = (bf16*)(ws + (72u << 20));    // 16 MB  [B,H,64,T]
  bf16* ao = (bf16*)(ws + (88u << 20));     // 16 MB  [8192][1024]

  cvt_f32_bf16<<<8192, 256, 0, stream>>>(x, xb);
  transpose_f32_bf16<<<dim3(96, 32), dim3(32, 8), 0, stream>>>(wqkv, wqkvt, 1024, 3072);
  transpose_f32_bf16<<<dim3(32, 32), dim3(32, 8), 0, stream>>>(wo, wot, 1024, 1024);
  gemm_bt<0><<<dim3(24, 64), 256, 0, stream>>>(xb, wqkvt, qb, kb, vb, nullptr,
                                               B_ * T_, 3 * D_, D_);
  transpose_v<<<dim3(64, 64), dim3(32, 8), 0, stream>>>(vb, vtb);
  attn_kernel<<<4096, 64, 0, stream>>>(qb, kb, vtb, ao);
  gemm_bt<1><<<dim3(8, 64), 256, 0, stream>>>(ao, wot, nullptr, nullptr, nullptr, out,
                                              B_ * T_, D_, D_);
}

// Round 8
// 238.685 us; speedup vs baseline: 1.1871x; 1.0114x over previous
//
#include <hip/hip_runtime.h>
#include <hip/hip_bf16.h>

#define B_ 4
#define T_ 2048
#define D_ 1024
#define H_ 16
#define HD_ 64

typedef __bf16 bf16;
typedef __bf16 bf16x8 __attribute__((ext_vector_type(8)));
typedef __bf16 bf16x4 __attribute__((ext_vector_type(4)));
typedef float f32x4 __attribute__((ext_vector_type(4)));
typedef float f32x16 __attribute__((ext_vector_type(16)));

#define MFMA16(a, b, c) __builtin_amdgcn_mfma_f32_16x16x32_bf16(a, b, c, 0, 0, 0)
#define MFMA32(a, b, c) __builtin_amdgcn_mfma_f32_32x32x16_bf16(a, b, c, 0, 0, 0)

__device__ inline void gld_lds16(const bf16* g, bf16* l) {
  __builtin_amdgcn_global_load_lds((const __attribute__((address_space(1))) void*)g,
                                   (__attribute__((address_space(3))) void*)l, 16, 0, 0);
}

__device__ inline unsigned pkbf16(float a, float b) {
  unsigned r;
  asm("v_cvt_pk_bf16_f32 %0, %1, %2" : "=v"(r) : "v"(a), "v"(b));
  return r;
}
__device__ inline void pl32swap(unsigned& x, unsigned& y) {
  asm("v_permlane32_swap_b32 %0, %1" : "+v"(x), "+v"(y));
}

// pack 8 consecutive-kv P values (this lane + partner lane) into one B-frag
#define PACKJ(dst, S, base)                        \
  {                                                \
    unsigned w0 = pkbf16(S[base + 0], S[base + 1]); \
    unsigned w2 = pkbf16(S[base + 4], S[base + 5]); \
    pl32swap(w0, w2);                              \
    unsigned w1 = pkbf16(S[base + 2], S[base + 3]); \
    unsigned w3 = pkbf16(S[base + 6], S[base + 7]); \
    pl32swap(w1, w3);                              \
    int4 wi = {(int)w0, (int)w1, (int)w2, (int)w3}; \
    dst = __builtin_bit_cast(bf16x8, wi);          \
  }

// ---------------- convert x f32 -> bf16 ----------------
__global__ void cvt_f32_bf16(const float* __restrict__ in, bf16* __restrict__ out) {
  int i = (blockIdx.x * 256 + threadIdx.x) * 4;
  float4 v = *(const float4*)(in + i);
  bf16x4 o = {(bf16)v.x, (bf16)v.y, (bf16)v.z, (bf16)v.w};
  *(bf16x4*)(out + i) = o;
}

// ---------------- transpose f32 [R][C] -> bf16 [C][R] ----------------
__global__ void transpose_f32_bf16(const float* __restrict__ in, bf16* __restrict__ out,
                                   int R, int C) {
  __shared__ float tile[32][33];
  int c0 = blockIdx.x * 32, r0 = blockIdx.y * 32;
  int tx = threadIdx.x, ty = threadIdx.y;
#pragma unroll
  for (int i = 0; i < 4; i++)
    tile[ty + i * 8][tx] = in[(size_t)(r0 + ty + i * 8) * C + c0 + tx];
  __syncthreads();
#pragma unroll
  for (int i = 0; i < 4; i++)
    out[(size_t)(c0 + ty + i * 8) * R + r0 + tx] = (bf16)tile[tx][ty + i * 8];
}

// ---------------- transpose V bf16 [bh][T][64] -> [bh][64][T] ----------------
__global__ void transpose_v(const bf16* __restrict__ in, bf16* __restrict__ out) {
  __shared__ bf16 tile[32][33];
  int bh = blockIdx.y;
  int t0 = blockIdx.x * 32;
  int tx = threadIdx.x, ty = threadIdx.y;
  const bf16* ib = in + (size_t)bh * T_ * HD_;
  bf16* ob = out + (size_t)bh * HD_ * T_;
#pragma unroll
  for (int d0 = 0; d0 < 64; d0 += 32) {
#pragma unroll
    for (int i = 0; i < 4; i++)
      tile[ty + i * 8][tx] = ib[(size_t)(t0 + ty + i * 8) * HD_ + d0 + tx];
    __syncthreads();
#pragma unroll
    for (int i = 0; i < 4; i++)
      ob[(size_t)(d0 + ty + i * 8) * T_ + t0 + tx] = tile[tx][ty + i * 8];
    __syncthreads();
  }
}

// ---------------- 128x128 bf16 GEMM, B transposed ([N][K]) ----------------
// 2-phase double-buffered staging (T3 minimum).
template <int EPI>
__global__ __launch_bounds__(256) void gemm_bt(const bf16* __restrict__ A,
                                               const bf16* __restrict__ Bt,
                                               bf16* __restrict__ qb, bf16* __restrict__ kb,
                                               bf16* __restrict__ vb, float* __restrict__ fout,
                                               int M, int N, int K) {
  __shared__ __align__(16) bf16 lds_a[2][128 * 32];
  __shared__ __align__(16) bf16 lds_b[2][128 * 32];
  int n0 = blockIdx.x * 128, m0 = blockIdx.y * 128;
  int tid = threadIdx.x, wave = tid >> 6, lane = tid & 63;
  int l16 = lane & 15, lhi = lane >> 4;
  int wr = wave >> 1, wc = wave & 1;
  f32x4 acc[4][4];
#pragma unroll
  for (int mt = 0; mt < 4; mt++)
#pragma unroll
    for (int nt = 0; nt < 4; nt++) acc[mt][nt] = (f32x4){0.f, 0.f, 0.f, 0.f};

  int sr = wave * 16 + (lane >> 2);
  int scol = (lane & 3) * 8;
  const bf16* ga = A + (size_t)(m0 + sr) * K + scol;
  const bf16* gb = Bt + (size_t)(n0 + sr) * K + scol;

  auto STAGE = [&](int buf, int k0) {
    gld_lds16(ga + k0, &lds_a[buf][wave * 512]);
    gld_lds16(ga + (size_t)64 * K + k0, &lds_a[buf][2048 + wave * 512]);
    gld_lds16(gb + k0, &lds_b[buf][wave * 512]);
    gld_lds16(gb + (size_t)64 * K + k0, &lds_b[buf][2048 + wave * 512]);
  };

  STAGE(0, 0);
  __syncthreads();
  int NT = K >> 5;
  for (int t = 0; t < NT; t++) {
    if (t + 1 < NT) STAGE((t + 1) & 1, (t + 1) * 32);
    const bf16* la = lds_a[t & 1];
    const bf16* lb = lds_b[t & 1];
    bf16x8 af[4], bfr[4];
#pragma unroll
    for (int mt = 0; mt < 4; mt++)
      af[mt] = *(const bf16x8*)&la[(wr * 64 + mt * 16 + l16) * 32 + 8 * lhi];
#pragma unroll
    for (int nt = 0; nt < 4; nt++)
      bfr[nt] = *(const bf16x8*)&lb[(wc * 64 + nt * 16 + l16) * 32 + 8 * lhi];
    __builtin_amdgcn_s_setprio(1);
#pragma unroll
    for (int mt = 0; mt < 4; mt++)
#pragma unroll
      for (int nt = 0; nt < 4; nt++) acc[mt][nt] = MFMA16(af[mt], bfr[nt], acc[mt][nt]);
    __builtin_amdgcn_s_setprio(0);
    __syncthreads();
  }

#pragma unroll
  for (int mt = 0; mt < 4; mt++)
#pragma unroll
    for (int nt = 0; nt < 4; nt++)
#pragma unroll
      for (int rr = 0; rr < 4; rr++) {
        int row = m0 + wr * 64 + mt * 16 + 4 * lhi + rr;
        int col = n0 + wc * 64 + nt * 16 + l16;
        float v = acc[mt][nt][rr];
        if (EPI == 0) {
          int b = row >> 11, t = row & (T_ - 1);
          int sec = col >> 10, c2 = col & 1023;
          int h = c2 >> 6, d = c2 & 63;
          size_t idx = ((size_t)(b * H_ + h) * T_ + t) * HD_ + d;
          if (sec == 0)
            qb[idx] = (bf16)(v * 0.045084439f);  // D^-0.5 * log2(e): exp2-domain softmax
          else if (sec == 1)
            kb[idx] = (bf16)v;
          else
            vb[idx] = (bf16)v;
        } else {
          fout[(size_t)row * N + col] = v;
        }
      }
}

// ---------------- causal flash attention v8 ----------------
// Balanced pairing: wave handles chunks (63-p) then (p) -> uniform 33 tiles
// per wave; grid 2048 1-wave blocks = flat 2 waves/SIMD for whole kernel.
// Cross-half reductions via __shfl_xor (R6-proven; the single-asm-block
// mov+permlane32_swap variant hit an intra-asm hazard -> wrong results).
__global__ __launch_bounds__(64) void attn_kernel(const bf16* __restrict__ qbuf,
                                                  const bf16* __restrict__ kbuf,
                                                  const bf16* __restrict__ vtbuf,
                                                  bf16* __restrict__ obuf) {
  __shared__ float tlds[64 * 33];
  int bid = blockIdx.x;
  int bh = (bid & 7) * 8 + ((bid >> 3) & 7);
  int p = bid >> 6;  // 0..31
  int lane = threadIdx.x;
  int q = lane & 31, hi = lane >> 5;

  const bf16* Q = qbuf + (size_t)bh * T_ * HD_;
  const bf16* Kg = kbuf + (size_t)bh * T_ * HD_;
  const bf16* Vt = vtbuf + (size_t)bh * HD_ * T_;
  const bf16* kbase = Kg + (size_t)q * HD_ + hi * 8;
  const bf16* vbase = Vt + (size_t)q * T_ + hi * 8;
  int b = bh >> 4, h = bh & 15;

#pragma unroll 1
  for (int half = 0; half < 2; ++half) {
    int qw = (half ? p : 63 - p) * 32;

    bf16x8 qf[4];
#pragma unroll
    for (int j = 0; j < 4; j++)
      qf[j] = *(const bf16x8*)(Q + (size_t)(qw + q) * HD_ + j * 16 + hi * 8);

    f32x16 o1, o2;
#pragma unroll
    for (int r = 0; r < 16; r++) {
      o1[r] = 0.f;
      o2[r] = 0.f;
    }
    float m_r = -1e30f, l_r = 0.f;
    int nt = qw / 64 + 1;

    bf16x8 kA[8], kB[8];
#pragma unroll
    for (int j = 0; j < 4; j++) {
      kA[j] = *(const bf16x8*)(kbase + j * 16);
      kA[4 + j] = *(const bf16x8*)(kbase + 32 * HD_ + j * 16);
    }

    auto body = [&](bf16x8(&kc)[8], bf16x8(&kp)[8], int t) {
      int jb = t * 64;
      // ---- QK^T: S^T[kv][q] ----
      f32x16 s1, s2;
#pragma unroll
      for (int r = 0; r < 16; r++) {
        s1[r] = 0.f;
        s2[r] = 0.f;
      }
      __builtin_amdgcn_s_setprio(1);
#pragma unroll
      for (int j = 0; j < 4; j++) s1 = MFMA32(kc[j], qf[j], s1);
#pragma unroll
      for (int j = 0; j < 4; j++) s2 = MFMA32(kc[4 + j], qf[j], s2);
      __builtin_amdgcn_s_setprio(0);
      // ---- prefetch next K tile (hidden under softmax+PV) ----
      if (t + 1 < nt) {
        int jn = (jb + 64) * HD_;
#pragma unroll
        for (int j = 0; j < 4; j++) {
          kp[j] = *(const bf16x8*)(kbase + jn + j * 16);
          kp[4 + j] = *(const bf16x8*)(kbase + jn + 32 * HD_ + j * 16);
        }
      }
      // ---- V frags for current tile (independent of softmax) ----
      bf16x8 vf[8];
#pragma unroll
      for (int j = 0; j < 4; j++) {
        vf[j] = *(const bf16x8*)(vbase + jb + j * 16);
        vf[4 + j] = *(const bf16x8*)(vbase + 32 * T_ + jb + j * 16);
      }
      // ---- causal mask (last tile only) ----
      if (t == nt - 1) {
#pragma unroll
        for (int r = 0; r < 16; r++) {
          int kv = (r & 3) + 8 * (r >> 2) + 4 * hi;
          if (jb + kv > qw + q) s1[r] = -1e30f;
          if (jb + kv + 32 > qw + q) s2[r] = -1e30f;
        }
      }
      // ---- online softmax: tree max, exp2 domain, defer-rescale ----
      float tm[8];
#pragma unroll
      for (int r = 0; r < 8; r++)
        tm[r] = fmaxf(fmaxf(s1[r], s1[r + 8]), fmaxf(s2[r], s2[r + 8]));
#pragma unroll
      for (int r = 0; r < 4; r++) tm[r] = fmaxf(tm[r], tm[r + 4]);
      float mx = fmaxf(fmaxf(tm[0], tm[1]), fmaxf(tm[2], tm[3]));
      mx = fmaxf(mx, __shfl_xor(mx, 32));
      bool defer = __all(mx <= m_r + 8.f);
      if (!defer) {
        float mn = fmaxf(m_r, mx);
        float sc = exp2f(m_r - mn);
        m_r = mn;
        l_r *= sc;
#pragma unroll
        for (int r = 0; r < 16; r++) {
          o1[r] *= sc;
          o2[r] *= sc;
        }
      }
#pragma unroll
      for (int r = 0; r < 16; r++) s1[r] = exp2f(s1[r] - m_r);
#pragma unroll
      for (int r = 0; r < 16; r++) s2[r] = exp2f(s2[r] - m_r);
      float ts[8];
#pragma unroll
      for (int r = 0; r < 8; r++) ts[r] = (s1[r] + s1[r + 8]) + (s2[r] + s2[r + 8]);
#pragma unroll
      for (int r = 0; r < 4; r++) ts[r] += ts[r + 4];
      float su = (ts[0] + ts[1]) + (ts[2] + ts[3]);
      su += __shfl_xor(su, 32);
      l_r += su;
      // ---- pack P into PV B-frags (in-register) ----
      bf16x8 pf0, pf1, pf2, pf3;
      PACKJ(pf0, s1, 0);
      PACKJ(pf1, s1, 8);
      PACKJ(pf2, s2, 0);
      PACKJ(pf3, s2, 8);
      // ---- PV: O^T[d][q] ----
      __builtin_amdgcn_s_setprio(1);
      o1 = MFMA32(vf[0], pf0, o1);
      o2 = MFMA32(vf[4], pf0, o2);
      o1 = MFMA32(vf[1], pf1, o1);
      o2 = MFMA32(vf[5], pf1, o2);
      o1 = MFMA32(vf[2], pf2, o1);
      o2 = MFMA32(vf[6], pf2, o2);
      o1 = MFMA32(vf[3], pf3, o1);
      o2 = MFMA32(vf[7], pf3, o2);
      __builtin_amdgcn_s_setprio(0);
    };

    int t = 0;
    while (true) {
      body(kA, kB, t);
      if (++t == nt) break;
      body(kB, kA, t);
      if (++t == nt) break;
    }

    // ---- epilogue: O^T -> LDS transpose -> coalesced bf16 stores ----
    float inv = 1.f / l_r;
#pragma unroll
    for (int r = 0; r < 16; r++) {
      int d = (r & 3) + 8 * (r >> 2) + 4 * hi;
      tlds[d * 33 + q] = o1[r] * inv;
      tlds[(32 + d) * 33 + q] = o2[r] * inv;
    }
    __syncthreads();
#pragma unroll
    for (int pass = 0; pass < 4; pass++) {
      int row = qw + pass * 8 + (lane >> 3);
      int dcol = (lane & 7) * 8;
      bf16x8 ov;
#pragma unroll
      for (int e = 0; e < 8; e++) ov[e] = (bf16)tlds[(dcol + e) * 33 + pass * 8 + (lane >> 3)];
      *(bf16x8*)(obuf + ((size_t)(b * T_ + row)) * D_ + h * 64 + dcol) = ov;
    }
    __syncthreads();
  }
}

extern "C" void kernel_launch(void* const* d_in, const int* in_sizes, int n_in, void* d_out,
                              int out_size, void* d_ws, size_t ws_size, hipStream_t stream) {
  const float* x = (const float*)d_in[0];
  const float* wqkv = (const float*)d_in[1];
  const float* wo = (const float*)d_in[2];
  float* out = (float*)d_out;
  char* ws = (char*)d_ws;

  bf16* xb = (bf16*)ws;                     // 16 MB  [8192][1024]
  bf16* wqkvt = (bf16*)(ws + (16u << 20));  // 6 MB   [3072][1024]
  bf16* wot = (bf16*)(ws + (22u << 20));    // 2 MB   [1024][1024]
  bf16* qb = (bf16*)(ws + (24u << 20));     // 16 MB  [B,H,T,64]
  bf16* kb = (bf16*)(ws + (40u << 20));     // 16 MB  [B,H,T,64]
  bf16* vb = (bf16*)(ws + (56u << 20));     // 16 MB  [B,H,T,64]
  bf16* vtb = (bf16*)(ws + (72u << 20));    // 16 MB  [B,H,64,T]
  bf16* ao = (bf16*)(ws + (88u << 20));     // 16 MB  [8192][1024]

  cvt_f32_bf16<<<8192, 256, 0, stream>>>(x, xb);
  transpose_f32_bf16<<<dim3(96, 32), dim3(32, 8), 0, stream>>>(wqkv, wqkvt, 1024, 3072);
  transpose_f32_bf16<<<dim3(32, 32), dim3(32, 8), 0, stream>>>(wo, wot, 1024, 1024);
  gemm_bt<0><<<dim3(24, 64), 256, 0, stream>>>(xb, wqkvt, qb, kb, vb, nullptr,
                                               B_ * T_, 3 * D_, D_);
  transpose_v<<<dim3(64, 64), dim3(32, 8), 0, stream>>>(vb, vtb);
  attn_kernel<<<2048, 64, 0, stream>>>(qb, kb, vtb, ao);
  gemm_bt<1><<<dim3(8, 64), 256, 0, stream>>>(ao, wot, nullptr, nullptr, nullptr, out,
                                              B_ * T_, D_, D_);
}